// Round 8
// baseline (105.530 us; speedup 1.0000x reference)
//
#include <hip/hip_runtime.h>
#include <math.h>

#define HW 9216      // 96*96
#define NSTRIP 288   // HW/32 row-tiles (worst case)
#define NCH 12       // j-chunk count (argmax grid.y); 18*12*2=432 blocks <= 512
                     // co-resident (2 blocks/CU) -> ONE scheduling round (r7: 576
                     // blocks = 512 + 64 stragglers, ~2x makespan)
#define EPSN 1e-8f

typedef _Float16 f16x8  __attribute__((ext_vector_type(8)));
typedef float    f32x16 __attribute__((ext_vector_type(16)));

// ---------------- kernel 1: prep = scan + norm + fp16x2 split + pack ------
// (verified round 7) Every block redundantly recomputes the compact scan
// (mask is 36KB, L2-resident) into an LDS slot table, then packs in position
// order — no compact->pack launch gap.
//   slot16[p] = compact slot | (flag<<15)
// ilist/jlist ASCENDING in original position (first-max tie-break compares
// compact j; ascending compact == ascending original). Block 0 also writes
// ilist/jlist/counts to global for argmax/epilogue.
// Pack: 4 threads per (b,p), 16 channels each; x reads are full 64B
// segments; split a = ah + al/2048 (ah=fp16(a), al=fp16((a-ah)*2048),
// residual exact by Sterbenz).
// PACKED LAYOUT (must match argmax loads exactly):
//   P[b][tile][ks][lane][e], tile=slot>>5, lane=g*32+(slot&31), k=ks*16+g*8+e.
// aH/aL = raw flagged rows (i side); bH/bL = normalized unflagged rows.
// NO zero-fill: tail-tile slots keep poison; argmax guards every use
// (j<nj scan guard, il<ni commit guard; 0xAA f16 is finite).
__global__ __launch_bounds__(256) void prep_kernel(
    const float* __restrict__ x, const int* __restrict__ mask,
    int* __restrict__ ilist, int* __restrict__ jlist, int* __restrict__ counts,
    _Float16* __restrict__ aH, _Float16* __restrict__ aL,
    _Float16* __restrict__ bH, _Float16* __restrict__ bL,
    unsigned long long* __restrict__ amax)
{
    __shared__ unsigned short slot16[HW];            // 18432 B
    __shared__ int wsum[4];
    int tid = threadIdx.x;
    // ---- phase 1: redundant compact scan (every block; all-uniform barriers)
    int base = tid * 36;
    const int4* mp4 = (const int4*)mask + tid * 9;   // 36 ints = 9 x int4, aligned
    unsigned long long fl = 0ull; int cnt = 0;
#pragma unroll
    for (int k4 = 0; k4 < 9; k4++) {
        int4 m4 = mp4[k4];
        int f0 = (m4.x >= 1), f1 = (m4.y >= 1), f2 = (m4.z >= 1), f3 = (m4.w >= 1);
        fl |= ((unsigned long long)f0 << (k4 * 4)) | ((unsigned long long)f1 << (k4 * 4 + 1)) |
              ((unsigned long long)f2 << (k4 * 4 + 2)) | ((unsigned long long)f3 << (k4 * 4 + 3));
        cnt += f0 + f1 + f2 + f3;
    }
    int lane = tid & 63, wave = tid >> 6;
    int v = cnt;
#pragma unroll
    for (int off = 1; off < 64; off <<= 1) {
        int u = __shfl_up(v, off, 64);
        if (lane >= off) v += u;
    }
    if (lane == 63) wsum[wave] = v;
    __syncthreads();
    int woff = 0;
#pragma unroll
    for (int w = 0; w < 4; w++) if (w < wave) woff += wsum[w];
    int incl = v + woff;
    int excl = incl - cnt;
    int posF = excl, posU = base - excl;
    bool wl = (blockIdx.x == 0);                     // only block 0 writes lists
#pragma unroll
    for (int k = 0; k < 36; k++) {
        int p = base + k;
        if ((fl >> k) & 1ull) { slot16[p] = (unsigned short)(posF | 0x8000); if (wl) ilist[posF] = p; posF++; }
        else                  { slot16[p] = (unsigned short)posU;            if (wl) jlist[posU] = p; posU++; }
    }
    if (wl && tid == 255) { counts[0] = incl; counts[1] = HW - incl; }
    __syncthreads();
    // ---- phase 2: norm + split + pack (t spans 0..73727 over 288 blocks)
    int t = blockIdx.x * 256 + tid;
    int sub = t & 63;
    int q = sub >> 4;                                // channel quarter
    int pb = ((t >> 6) << 4) | (sub & 15);           // b*HW + p (wave = 16 consecutive p)
    int b = pb / HW, p = pb - b * HW;
    const float* xl = x + (size_t)(b * 128 + 64) * HW + p;
    float vv[16]; float ss = 0.f;
#pragma unroll
    for (int e = 0; e < 16; e++) { float w0 = xl[(size_t)(q * 16 + e) * HW]; vv[e] = w0; ss = fmaf(w0, w0, ss); }
    ss += __shfl_xor(ss, 16, 64);                    // reduce the 4 channel-quarters
    ss += __shfl_xor(ss, 32, 64);
    float inv = 1.0f / fmaxf(sqrtf(ss), EPSN);
    if (q == 0) amax[pb] = 0ull;                     // ws is poisoned pre-launch
    unsigned sl = slot16[p];
    int flagged = sl >> 15;
    int slot = sl & 0x7fff;
    float scale = flagged ? 1.0f : inv;              // a side raw, b side normalized
    int tile = slot >> 5, lnp = slot & 31;
    _Float16* dh = flagged ? aH : bH;
    _Float16* dl = flagged ? aL : bL;
#pragma unroll
    for (int h = 0; h < 2; h++) {                    // chunk cc = 2q+h: ks=q, g=h
        size_t off = ((((size_t)b * NSTRIP + tile) * 4 + q) * 64 + h * 32 + lnp) * 8;
        f16x8 hh, ll;
#pragma unroll
        for (int e = 0; e < 8; e++) {
            float w0 = vv[h * 8 + e] * scale;
            _Float16 hv = (_Float16)w0;
            hh[e] = hv; ll[e] = (_Float16)((w0 - (float)hv) * 2048.0f);
        }
        *(f16x8*)(dh + off) = hh; *(f16x8*)(dl + off) = ll;
    }
}

// ordered-float mapping: monotone bijection float -> uint32 under unsigned compare
__device__ __forceinline__ unsigned int ordf(float f) {
    unsigned int u = __float_as_uint(f);
    return (u & 0x80000000u) ? ~u : (u | 0x80000000u);
}

// ---------------- kernel 2: MFMA argmax (compacted), LDS-shared b-tiles ---
// D[j][i] = sum_c b[j][c]*a[i][c] via v_mfma_f32_32x32x16_f16, K=64 as 4
// k-steps, 3 passes (hh into cH; ah*bl + al*bh into cC, pre-scaled x2048).
// sim = cH + cC/2048; dropped al*bl/2048^2 ~ 2^-22.
// Each wave owns 64 i-rows (2 strips); the block's 4 waves share each 8KB
// b-tile via LDS (staged once per block, double-buffered, one barrier/tile).
// Register contents identical to verified rounds 2-7 (k = ks*16 + g*8 + e
// both operands; C/D: col=lane&31, row=(reg&3)+8*(reg>>2)+4*(lane>>5)).
// Tail waves (base>=ni) do NOT exit: they stage + hit barriers; results
// blocked by the il<ni commit guard (poison f16 is finite).
// Scan: full-tile fast path (wave-uniform jb+32<=nj) skips the per-slot
// j<nj compare; only the globally-last partial tile takes the guarded path.
// First-max tie-break: per-lane rows scanned ascending with strict >, then
// packed-key (ordf(val)<<32 | ~j) merged across lane halves and chunks.
__global__ __launch_bounds__(256, 2) void argmax_kernel(
    const _Float16* __restrict__ aH, const _Float16* __restrict__ aL,
    const _Float16* __restrict__ bH, const _Float16* __restrict__ bL,
    const int* __restrict__ ilist, const int* __restrict__ counts,
    unsigned long long* __restrict__ amax)
{
    int ni = counts[0];
    if (blockIdx.x * 256 >= ni) return;              // block-uniform exit
    int nj = counts[1];
    int njt = (nj + 31) >> 5;
    int tpc = (njt + NCH - 1) / NCH;
    int s = blockIdx.y;
    int jt0 = s * tpc, jt1 = min(jt0 + tpc, njt);
    if (jt0 >= jt1) return;                          // block-uniform (s,nj only)
    int b = blockIdx.z;
    int wave = threadIdx.x >> 6, l = threadIdx.x & 63;
    int base = (blockIdx.x * 4 + wave) * 64;         // may exceed ni (tail waves)
    int g = l >> 5, ln = l & 31;
    int strip0 = base >> 5;                          // < NSTRIP by grid bound

    __shared__ f16x8 lds[2][8][64];                  // 2 x 8KB double buffer

    // a-frags, register-resident (k = ks*16 + g*8 + e)
    const f16x8* apH = (const f16x8*)aH + ((size_t)b * NSTRIP + strip0) * 256 + l;
    const f16x8* apL = (const f16x8*)aL + ((size_t)b * NSTRIP + strip0) * 256 + l;
    f16x8 xh0 = apH[0],   xh1 = apH[64],  xh2 = apH[128], xh3 = apH[192];   // strip0 H
    f16x8 xl0 = apL[0],   xl1 = apL[64],  xl2 = apL[128], xl3 = apL[192];   // strip0 L
    f16x8 yh0 = apH[256], yh1 = apH[320], yh2 = apH[384], yh3 = apH[448];   // strip1 H
    f16x8 yl0 = apL[256], yl1 = apL[320], yl2 = apL[384], yl3 = apL[448];   // strip1 L

    // staging sources: wave owns fragments f0=2*wave, f0+1 (f<4: bH ks=f; else bL)
    int f0 = wave * 2;
    const f16x8* s0 = (const f16x8*)((f0 < 4) ? bH : bL) +
                      (size_t)b * NSTRIP * 256 + (size_t)(f0 & 3) * 64 + l;
    const f16x8* s1 = (const f16x8*)((f0 + 1 < 4) ? bH : bL) +
                      (size_t)b * NSTRIP * 256 + (size_t)((f0 + 1) & 3) * 64 + l;

    // prologue: stage tile jt0 into buf 0
    {
        f16x8 t0 = s0[(size_t)jt0 * 256];
        f16x8 t1 = s1[(size_t)jt0 * 256];
        lds[0][f0][l] = t0;
        lds[0][f0 + 1][l] = t1;
    }
    __syncthreads();

    float bv0 = -INFINITY, bv1 = -INFINITY;
    int bj0 = -1, bj1 = -1;
    int cur = 0;

    for (int jt = jt0; jt < jt1; ++jt, cur ^= 1) {
        // issue next-tile global loads early (complete under the MFMAs)
        f16x8 n0, n1;
        bool more = (jt + 1 < jt1);                  // block-uniform
        if (more) {
            n0 = s0[(size_t)(jt + 1) * 256];
            n1 = s1[(size_t)(jt + 1) * 256];
        }
        f16x8 bh0 = lds[cur][0][l], bh1 = lds[cur][1][l];
        f16x8 bh2 = lds[cur][2][l], bh3 = lds[cur][3][l];
        f16x8 bl0 = lds[cur][4][l], bl1 = lds[cur][5][l];
        f16x8 bl2 = lds[cur][6][l], bl3 = lds[cur][7][l];
        f32x16 cH0 = {}, cC0 = {}, cH1 = {}, cC1 = {};
        // strip 0
        cH0 = __builtin_amdgcn_mfma_f32_32x32x16_f16(bh0, xh0, cH0, 0, 0, 0);
        cC0 = __builtin_amdgcn_mfma_f32_32x32x16_f16(bh0, xl0, cC0, 0, 0, 0);
        cC0 = __builtin_amdgcn_mfma_f32_32x32x16_f16(bl0, xh0, cC0, 0, 0, 0);
        cH0 = __builtin_amdgcn_mfma_f32_32x32x16_f16(bh1, xh1, cH0, 0, 0, 0);
        cC0 = __builtin_amdgcn_mfma_f32_32x32x16_f16(bh1, xl1, cC0, 0, 0, 0);
        cC0 = __builtin_amdgcn_mfma_f32_32x32x16_f16(bl1, xh1, cC0, 0, 0, 0);
        cH0 = __builtin_amdgcn_mfma_f32_32x32x16_f16(bh2, xh2, cH0, 0, 0, 0);
        cC0 = __builtin_amdgcn_mfma_f32_32x32x16_f16(bh2, xl2, cC0, 0, 0, 0);
        cC0 = __builtin_amdgcn_mfma_f32_32x32x16_f16(bl2, xh2, cC0, 0, 0, 0);
        cH0 = __builtin_amdgcn_mfma_f32_32x32x16_f16(bh3, xh3, cH0, 0, 0, 0);
        cC0 = __builtin_amdgcn_mfma_f32_32x32x16_f16(bh3, xl3, cC0, 0, 0, 0);
        cC0 = __builtin_amdgcn_mfma_f32_32x32x16_f16(bl3, xh3, cC0, 0, 0, 0);
        // strip 1 (same b-frags)
        cH1 = __builtin_amdgcn_mfma_f32_32x32x16_f16(bh0, yh0, cH1, 0, 0, 0);
        cC1 = __builtin_amdgcn_mfma_f32_32x32x16_f16(bh0, yl0, cC1, 0, 0, 0);
        cC1 = __builtin_amdgcn_mfma_f32_32x32x16_f16(bl0, yh0, cC1, 0, 0, 0);
        cH1 = __builtin_amdgcn_mfma_f32_32x32x16_f16(bh1, yh1, cH1, 0, 0, 0);
        cC1 = __builtin_amdgcn_mfma_f32_32x32x16_f16(bh1, yl1, cC1, 0, 0, 0);
        cC1 = __builtin_amdgcn_mfma_f32_32x32x16_f16(bl1, yh1, cC1, 0, 0, 0);
        cH1 = __builtin_amdgcn_mfma_f32_32x32x16_f16(bh2, yh2, cH1, 0, 0, 0);
        cC1 = __builtin_amdgcn_mfma_f32_32x32x16_f16(bh2, yl2, cC1, 0, 0, 0);
        cC1 = __builtin_amdgcn_mfma_f32_32x32x16_f16(bl2, yh2, cC1, 0, 0, 0);
        cH1 = __builtin_amdgcn_mfma_f32_32x32x16_f16(bh3, yh3, cH1, 0, 0, 0);
        cC1 = __builtin_amdgcn_mfma_f32_32x32x16_f16(bh3, yl3, cC1, 0, 0, 0);
        cC1 = __builtin_amdgcn_mfma_f32_32x32x16_f16(bl3, yh3, cC1, 0, 0, 0);
        int jb = jt << 5;
        // ascending-j scan, strict > => first max
        if (jb + 32 <= nj) {                         // full tile (wave-uniform): no j-guard
#pragma unroll
            for (int r = 0; r < 16; ++r) {
                int row = (r & 3) + 8 * (r >> 2) + 4 * g;
                int j = jb + row;
                float v0 = fmaf(cC0[r], 4.8828125e-4f /*2^-11*/, cH0[r]);
                float v1 = fmaf(cC1[r], 4.8828125e-4f, cH1[r]);
                if (v0 > bv0) { bv0 = v0; bj0 = j; }
                if (v1 > bv1) { bv1 = v1; bj1 = j; }
            }
        } else {                                     // last partial tile: poison guarded
#pragma unroll
            for (int r = 0; r < 16; ++r) {
                int row = (r & 3) + 8 * (r >> 2) + 4 * g;
                int j = jb + row;
                float v0 = fmaf(cC0[r], 4.8828125e-4f, cH0[r]);
                float v1 = fmaf(cC1[r], 4.8828125e-4f, cH1[r]);
                if (j < nj && v0 > bv0) { bv0 = v0; bj0 = j; }
                if (j < nj && v1 > bv1) { bv1 = v1; bj1 = j; }
            }
        }
        if (more) {
            lds[cur ^ 1][f0][l] = n0;
            lds[cur ^ 1][f0 + 1][l] = n1;
        }
        __syncthreads();
    }

    unsigned long long k0 = ((unsigned long long)ordf(bv0) << 32) |
                            (unsigned long long)(~(unsigned int)bj0);
    unsigned long long k1 = ((unsigned long long)ordf(bv1) << 32) |
                            (unsigned long long)(~(unsigned int)bj1);
    unsigned long long o0 = __shfl_xor(k0, 32, 64);   // merge lane halves
    unsigned long long o1 = __shfl_xor(k1, 32, 64);
    if (o0 > k0) k0 = o0;
    if (o1 > k1) k1 = o1;
    int il0 = base + ln, il1 = base + 32 + ln;
    // commit iff i-slot real AND a finite candidate exists (high word > ordf(-inf))
    if (g == 0) {
        if (il0 < ni && (unsigned)(k0 >> 32) > 0x007FFFFFu)
            atomicMax(&amax[(size_t)b * HW + ilist[il0]], k0);
        if (il1 < ni && (unsigned)(k1 >> 32) > 0x007FFFFFu)
            atomicMax(&amax[(size_t)b * HW + ilist[il1]], k1);
    }
}

// ---------------- kernel 3: fused epilogue (copy + decode + gather) -------
// Keys store compact j -> decode via jlist. amax==0 (nj==0: no valid j)
// falls back to j=0 = reference argmax of an all-NEG row.
__global__ void epilogue_kernel(const float4* __restrict__ x4, const float* __restrict__ x,
                                const int* __restrict__ mask,
                                const unsigned long long* __restrict__ amax,
                                const int* __restrict__ jlist, float4* __restrict__ out4) {
    const int q = HW / 4;                            // 2304
    int t = blockIdx.x * blockDim.x + threadIdx.x;   // 0 .. 2*192*q-1
    if (t >= 2 * 192 * q) return;
    int pos4 = t % q;
    int c = (t / q) % 192;
    int b = t / (192 * q);
    if (c < 128) {
        out4[t] = x4[((size_t)b * 128 + c) * q + pos4];
    } else {
        float4 v = make_float4(0.f, 0.f, 0.f, 0.f);
        float* vp = &v.x;
        int pos = pos4 * 4;
        const float* xf = x + (size_t)(b * 128 + (c - 128)) * HW;
#pragma unroll
        for (int k = 0; k < 4; k++) {
            int p = pos + k;
            if (mask[p] >= 1) {
                unsigned long long key = amax[(size_t)b * HW + p];
                int j = 0;
                if (key != 0ull) j = jlist[(int)(~(unsigned int)key)];
                vp[k] = xf[j];
            }
        }
        out4[t] = v;
    }
}

extern "C" void kernel_launch(void* const* d_in, const int* in_sizes, int n_in,
                              void* d_out, int out_size, void* d_ws, size_t ws_size,
                              hipStream_t stream) {
    const float* x = (const float*)d_in[0];
    const int* mask = (const int*)d_in[1];
    float4* out4 = (float4*)d_out;

    // workspace layout (frag bases 128B-aligned):
    //   counts @0 (8B) | ilist @128 (36864) | jlist @36992 (36864)
    //   amax @73856 (147456)
    //   aH @221312 | aL | bH | bL  -- each 2*288*4*64*8 f16 = 2359296 B
    // total = 221312 + 4*2359296 = 9658496 B
    char* ws = (char*)d_ws;
    int*   counts = (int*)ws;
    int*   ilist  = (int*)(ws + 128);
    int*   jlist  = (int*)(ws + 36992);
    unsigned long long* amax = (unsigned long long*)(ws + 73856);
    _Float16* aH = (_Float16*)(ws + 221312);
    _Float16* aL = (_Float16*)(ws + 221312 + 1 * 2359296);
    _Float16* bH = (_Float16*)(ws + 221312 + 2 * 2359296);
    _Float16* bL = (_Float16*)(ws + 221312 + 3 * 2359296);

    // 1) prep: per-block redundant compact scan + norm + split + compacted
    //    fragment pack + amax zero (one launch, no compact->pack gap)
    prep_kernel<<<288, 256, 0, stream>>>(x, mask, ilist, jlist, counts,
                                         aH, aL, bH, bL, amax);
    // 2) MFMA argmax over compacted space (grid: i-groups, j-chunks, batch)
    {
        dim3 grid(NSTRIP / 8, NCH, 2);               // 36 x 12 x 2 (dead blocks exit)
        argmax_kernel<<<grid, 256, 0, stream>>>(aH, aL, bH, bL, ilist, counts, amax);
    }
    // 3) fused copy + decode + gather
    {
        int n = 2 * 192 * (HW / 4);
        epilogue_kernel<<<(n + 255) / 256, 256, 0, stream>>>((const float4*)x, x, mask,
                                                             amax, jlist, out4);
    }
}

// Round 9
// 97.404 us; speedup vs baseline: 1.0834x; 1.0834x over previous
//
#include <hip/hip_runtime.h>
#include <math.h>

#define HW 9216      // 96*96
#define NSTRIP 288   // HW/32 row-tiles (worst case)
#define NCH 18       // j-chunk count; occupancy is 3 blocks/CU (~768 capacity):
                     // active = ceil(ni/256)*NCH*2 <= 684 even at ni~4860 ->
                     // ONE scheduling round of 8-tile blocks (r8 lesson: longer
                     // blocks at same rounds = slower; r7's 9-tile was 1 round)
#define NCOPY 160    // prep copy-blocks (passthrough out[:,:128] = x[:,:128])
#define EPSN 1e-8f

typedef _Float16 f16x8  __attribute__((ext_vector_type(8)));
typedef float    f32x16 __attribute__((ext_vector_type(16)));

// ---------------- kernel 1: prep = scan + norm + split + pack + COPY ------
// (verified round 7, + copy blocks) Blocks < 288: every block redundantly
// recomputes the compact scan (mask 36KB, L2-resident) into an LDS slot
// table, then packs in position order — no compact->pack launch gap.
//   slot16[p] = compact slot | (flag<<15)
// Blocks >= 288: amax-INDEPENDENT passthrough copy of out channels [0,128)
// (float4), hoisted here from the epilogue so it overlaps prep's
// latency-bound phases instead of serializing after argmax. These blocks
// never touch LDS/barriers (per-block barriers only — safe).
// ilist/jlist ASCENDING in original position (first-max tie-break compares
// compact j; ascending compact == ascending original). Block 0 writes lists.
// Pack: 4 threads per (b,p), 16 channels each; x reads full 64B segments;
// split a = ah + al/2048 (ah=fp16(a), al=fp16((a-ah)*2048), Sterbenz-exact).
// PACKED LAYOUT (must match argmax loads exactly):
//   P[b][tile][ks][lane][e], tile=slot>>5, lane=g*32+(slot&31), k=ks*16+g*8+e.
// aH/aL = raw flagged rows (i side); bH/bL = normalized unflagged rows.
// NO zero-fill: tail-tile slots keep poison; argmax guards every use.
__global__ __launch_bounds__(256) void prep_kernel(
    const float* __restrict__ x, const float4* __restrict__ x4,
    const int* __restrict__ mask,
    int* __restrict__ ilist, int* __restrict__ jlist, int* __restrict__ counts,
    _Float16* __restrict__ aH, _Float16* __restrict__ aL,
    _Float16* __restrict__ bH, _Float16* __restrict__ bL,
    unsigned long long* __restrict__ amax, float4* __restrict__ out4)
{
    __shared__ unsigned short slot16[HW];            // 18432 B
    __shared__ int wsum[4];
    int tid = threadIdx.x;
    if (blockIdx.x >= 288) {                         // ---- copy blocks ----
        const int N = 128 * (HW / 4);                // float4 per batch, c<128
        for (int e = (blockIdx.x - 288) * 256 + tid; e < 2 * N; e += NCOPY * 256) {
            int b = e / N, rem = e - b * N;          // rem = c*2304 + pos4
            out4[(size_t)b * 192 * (HW / 4) + rem] = x4[(size_t)b * N + rem];
        }
        return;
    }
    // ---- phase 1: redundant compact scan (every compute block)
    int base = tid * 36;
    const int4* mp4 = (const int4*)mask + tid * 9;   // 36 ints = 9 x int4, aligned
    unsigned long long fl = 0ull; int cnt = 0;
#pragma unroll
    for (int k4 = 0; k4 < 9; k4++) {
        int4 m4 = mp4[k4];
        int f0 = (m4.x >= 1), f1 = (m4.y >= 1), f2 = (m4.z >= 1), f3 = (m4.w >= 1);
        fl |= ((unsigned long long)f0 << (k4 * 4)) | ((unsigned long long)f1 << (k4 * 4 + 1)) |
              ((unsigned long long)f2 << (k4 * 4 + 2)) | ((unsigned long long)f3 << (k4 * 4 + 3));
        cnt += f0 + f1 + f2 + f3;
    }
    int lane = tid & 63, wave = tid >> 6;
    int v = cnt;
#pragma unroll
    for (int off = 1; off < 64; off <<= 1) {
        int u = __shfl_up(v, off, 64);
        if (lane >= off) v += u;
    }
    if (lane == 63) wsum[wave] = v;
    __syncthreads();
    int woff = 0;
#pragma unroll
    for (int w = 0; w < 4; w++) if (w < wave) woff += wsum[w];
    int incl = v + woff;
    int excl = incl - cnt;
    int posF = excl, posU = base - excl;
    bool wl = (blockIdx.x == 0);                     // only block 0 writes lists
#pragma unroll
    for (int k = 0; k < 36; k++) {
        int p = base + k;
        if ((fl >> k) & 1ull) { slot16[p] = (unsigned short)(posF | 0x8000); if (wl) ilist[posF] = p; posF++; }
        else                  { slot16[p] = (unsigned short)posU;            if (wl) jlist[posU] = p; posU++; }
    }
    if (wl && tid == 255) { counts[0] = incl; counts[1] = HW - incl; }
    __syncthreads();
    // ---- phase 2: norm + split + pack (t spans 0..73727 over 288 blocks)
    int t = blockIdx.x * 256 + tid;
    int sub = t & 63;
    int q = sub >> 4;                                // channel quarter
    int pb = ((t >> 6) << 4) | (sub & 15);           // b*HW + p (wave = 16 consecutive p)
    int b = pb / HW, p = pb - b * HW;
    const float* xl = x + (size_t)(b * 128 + 64) * HW + p;
    float vv[16]; float ss = 0.f;
#pragma unroll
    for (int e = 0; e < 16; e++) { float w0 = xl[(size_t)(q * 16 + e) * HW]; vv[e] = w0; ss = fmaf(w0, w0, ss); }
    ss += __shfl_xor(ss, 16, 64);                    // reduce the 4 channel-quarters
    ss += __shfl_xor(ss, 32, 64);
    float inv = 1.0f / fmaxf(sqrtf(ss), EPSN);
    if (q == 0) amax[pb] = 0ull;                     // ws is poisoned pre-launch
    unsigned sl = slot16[p];
    int flagged = sl >> 15;
    int slot = sl & 0x7fff;
    float scale = flagged ? 1.0f : inv;              // a side raw, b side normalized
    int tile = slot >> 5, lnp = slot & 31;
    _Float16* dh = flagged ? aH : bH;
    _Float16* dl = flagged ? aL : bL;
#pragma unroll
    for (int h = 0; h < 2; h++) {                    // chunk cc = 2q+h: ks=q, g=h
        size_t off = ((((size_t)b * NSTRIP + tile) * 4 + q) * 64 + h * 32 + lnp) * 8;
        f16x8 hh, ll;
#pragma unroll
        for (int e = 0; e < 8; e++) {
            float w0 = vv[h * 8 + e] * scale;
            _Float16 hv = (_Float16)w0;
            hh[e] = hv; ll[e] = (_Float16)((w0 - (float)hv) * 2048.0f);
        }
        *(f16x8*)(dh + off) = hh; *(f16x8*)(dl + off) = ll;
    }
}

// ordered-float mapping: monotone bijection float -> uint32 under unsigned compare
__device__ __forceinline__ unsigned int ordf(float f) {
    unsigned int u = __float_as_uint(f);
    return (u & 0x80000000u) ? ~u : (u | 0x80000000u);
}

// ---------------- kernel 2: MFMA argmax (compacted), LDS-shared b-tiles ---
// D[j][i] = sum_c b[j][c]*a[i][c] via v_mfma_f32_32x32x16_f16, K=64 as 4
// k-steps, 3 passes (hh into cH; ah*bl + al*bh into cC, pre-scaled x2048).
// sim = cH + cC/2048; dropped al*bl/2048^2 ~ 2^-22.
// Each wave owns 64 i-rows (2 strips); the block's 4 waves share each 8KB
// b-tile via LDS (staged once per block, double-buffered, one barrier/tile).
// Register contents identical to verified rounds 2-8 (k = ks*16 + g*8 + e
// both operands; C/D: col=lane&31, row=(reg&3)+8*(reg>>2)+4*(lane>>5)).
// Tail waves (base>=ni) do NOT exit (stage + barriers); il<ni commit guard.
// Scan: full-tile fast path (wave-uniform jb+32<=nj) skips per-slot j<nj.
// First-max tie-break: ascending scan, strict >, packed-key
// (ordf(val)<<32 | ~j) merged across lane halves and chunks via atomicMax.
__global__ __launch_bounds__(256, 2) void argmax_kernel(
    const _Float16* __restrict__ aH, const _Float16* __restrict__ aL,
    const _Float16* __restrict__ bH, const _Float16* __restrict__ bL,
    const int* __restrict__ ilist, const int* __restrict__ counts,
    unsigned long long* __restrict__ amax)
{
    int ni = counts[0];
    if (blockIdx.x * 256 >= ni) return;              // block-uniform exit
    int nj = counts[1];
    int njt = (nj + 31) >> 5;
    int tpc = (njt + NCH - 1) / NCH;
    int s = blockIdx.y;
    int jt0 = s * tpc, jt1 = min(jt0 + tpc, njt);
    if (jt0 >= jt1) return;                          // block-uniform (s,nj only)
    int b = blockIdx.z;
    int wave = threadIdx.x >> 6, l = threadIdx.x & 63;
    int base = (blockIdx.x * 4 + wave) * 64;         // may exceed ni (tail waves)
    int g = l >> 5, ln = l & 31;
    int strip0 = base >> 5;                          // < NSTRIP by grid bound

    __shared__ f16x8 lds[2][8][64];                  // 2 x 8KB double buffer

    // a-frags, register-resident (k = ks*16 + g*8 + e)
    const f16x8* apH = (const f16x8*)aH + ((size_t)b * NSTRIP + strip0) * 256 + l;
    const f16x8* apL = (const f16x8*)aL + ((size_t)b * NSTRIP + strip0) * 256 + l;
    f16x8 xh0 = apH[0],   xh1 = apH[64],  xh2 = apH[128], xh3 = apH[192];   // strip0 H
    f16x8 xl0 = apL[0],   xl1 = apL[64],  xl2 = apL[128], xl3 = apL[192];   // strip0 L
    f16x8 yh0 = apH[256], yh1 = apH[320], yh2 = apH[384], yh3 = apH[448];   // strip1 H
    f16x8 yl0 = apL[256], yl1 = apL[320], yl2 = apL[384], yl3 = apL[448];   // strip1 L

    // staging sources: wave owns fragments f0=2*wave, f0+1 (f<4: bH ks=f; else bL)
    int f0 = wave * 2;
    const f16x8* s0 = (const f16x8*)((f0 < 4) ? bH : bL) +
                      (size_t)b * NSTRIP * 256 + (size_t)(f0 & 3) * 64 + l;
    const f16x8* s1 = (const f16x8*)((f0 + 1 < 4) ? bH : bL) +
                      (size_t)b * NSTRIP * 256 + (size_t)((f0 + 1) & 3) * 64 + l;

    // prologue: stage tile jt0 into buf 0
    {
        f16x8 t0 = s0[(size_t)jt0 * 256];
        f16x8 t1 = s1[(size_t)jt0 * 256];
        lds[0][f0][l] = t0;
        lds[0][f0 + 1][l] = t1;
    }
    __syncthreads();

    float bv0 = -INFINITY, bv1 = -INFINITY;
    int bj0 = -1, bj1 = -1;
    int cur = 0;

    for (int jt = jt0; jt < jt1; ++jt, cur ^= 1) {
        // issue next-tile global loads early (complete under the MFMAs)
        f16x8 n0, n1;
        bool more = (jt + 1 < jt1);                  // block-uniform
        if (more) {
            n0 = s0[(size_t)(jt + 1) * 256];
            n1 = s1[(size_t)(jt + 1) * 256];
        }
        f16x8 bh0 = lds[cur][0][l], bh1 = lds[cur][1][l];
        f16x8 bh2 = lds[cur][2][l], bh3 = lds[cur][3][l];
        f16x8 bl0 = lds[cur][4][l], bl1 = lds[cur][5][l];
        f16x8 bl2 = lds[cur][6][l], bl3 = lds[cur][7][l];
        f32x16 cH0 = {}, cC0 = {}, cH1 = {}, cC1 = {};
        // strip 0
        cH0 = __builtin_amdgcn_mfma_f32_32x32x16_f16(bh0, xh0, cH0, 0, 0, 0);
        cC0 = __builtin_amdgcn_mfma_f32_32x32x16_f16(bh0, xl0, cC0, 0, 0, 0);
        cC0 = __builtin_amdgcn_mfma_f32_32x32x16_f16(bl0, xh0, cC0, 0, 0, 0);
        cH0 = __builtin_amdgcn_mfma_f32_32x32x16_f16(bh1, xh1, cH0, 0, 0, 0);
        cC0 = __builtin_amdgcn_mfma_f32_32x32x16_f16(bh1, xl1, cC0, 0, 0, 0);
        cC0 = __builtin_amdgcn_mfma_f32_32x32x16_f16(bl1, xh1, cC0, 0, 0, 0);
        cH0 = __builtin_amdgcn_mfma_f32_32x32x16_f16(bh2, xh2, cH0, 0, 0, 0);
        cC0 = __builtin_amdgcn_mfma_f32_32x32x16_f16(bh2, xl2, cC0, 0, 0, 0);
        cC0 = __builtin_amdgcn_mfma_f32_32x32x16_f16(bl2, xh2, cC0, 0, 0, 0);
        cH0 = __builtin_amdgcn_mfma_f32_32x32x16_f16(bh3, xh3, cH0, 0, 0, 0);
        cC0 = __builtin_amdgcn_mfma_f32_32x32x16_f16(bh3, xl3, cC0, 0, 0, 0);
        cC0 = __builtin_amdgcn_mfma_f32_32x32x16_f16(bl3, xh3, cC0, 0, 0, 0);
        // strip 1 (same b-frags)
        cH1 = __builtin_amdgcn_mfma_f32_32x32x16_f16(bh0, yh0, cH1, 0, 0, 0);
        cC1 = __builtin_amdgcn_mfma_f32_32x32x16_f16(bh0, yl0, cC1, 0, 0, 0);
        cC1 = __builtin_amdgcn_mfma_f32_32x32x16_f16(bl0, yh0, cC1, 0, 0, 0);
        cH1 = __builtin_amdgcn_mfma_f32_32x32x16_f16(bh1, yh1, cH1, 0, 0, 0);
        cC1 = __builtin_amdgcn_mfma_f32_32x32x16_f16(bh1, yl1, cC1, 0, 0, 0);
        cC1 = __builtin_amdgcn_mfma_f32_32x32x16_f16(bl1, yh1, cC1, 0, 0, 0);
        cH1 = __builtin_amdgcn_mfma_f32_32x32x16_f16(bh2, yh2, cH1, 0, 0, 0);
        cC1 = __builtin_amdgcn_mfma_f32_32x32x16_f16(bh2, yl2, cC1, 0, 0, 0);
        cC1 = __builtin_amdgcn_mfma_f32_32x32x16_f16(bl2, yh2, cC1, 0, 0, 0);
        cH1 = __builtin_amdgcn_mfma_f32_32x32x16_f16(bh3, yh3, cH1, 0, 0, 0);
        cC1 = __builtin_amdgcn_mfma_f32_32x32x16_f16(bh3, yl3, cC1, 0, 0, 0);
        cC1 = __builtin_amdgcn_mfma_f32_32x32x16_f16(bl3, yh3, cC1, 0, 0, 0);
        int jb = jt << 5;
        // ascending-j scan, strict > => first max
        if (jb + 32 <= nj) {                         // full tile (wave-uniform): no j-guard
#pragma unroll
            for (int r = 0; r < 16; ++r) {
                int row = (r & 3) + 8 * (r >> 2) + 4 * g;
                int j = jb + row;
                float v0 = fmaf(cC0[r], 4.8828125e-4f /*2^-11*/, cH0[r]);
                float v1 = fmaf(cC1[r], 4.8828125e-4f, cH1[r]);
                if (v0 > bv0) { bv0 = v0; bj0 = j; }
                if (v1 > bv1) { bv1 = v1; bj1 = j; }
            }
        } else {                                     // last partial tile: poison guarded
#pragma unroll
            for (int r = 0; r < 16; ++r) {
                int row = (r & 3) + 8 * (r >> 2) + 4 * g;
                int j = jb + row;
                float v0 = fmaf(cC0[r], 4.8828125e-4f, cH0[r]);
                float v1 = fmaf(cC1[r], 4.8828125e-4f, cH1[r]);
                if (j < nj && v0 > bv0) { bv0 = v0; bj0 = j; }
                if (j < nj && v1 > bv1) { bv1 = v1; bj1 = j; }
            }
        }
        if (more) {
            lds[cur ^ 1][f0][l] = n0;
            lds[cur ^ 1][f0 + 1][l] = n1;
        }
        __syncthreads();
    }

    unsigned long long k0 = ((unsigned long long)ordf(bv0) << 32) |
                            (unsigned long long)(~(unsigned int)bj0);
    unsigned long long k1 = ((unsigned long long)ordf(bv1) << 32) |
                            (unsigned long long)(~(unsigned int)bj1);
    unsigned long long o0 = __shfl_xor(k0, 32, 64);   // merge lane halves
    unsigned long long o1 = __shfl_xor(k1, 32, 64);
    if (o0 > k0) k0 = o0;
    if (o1 > k1) k1 = o1;
    int il0 = base + ln, il1 = base + 32 + ln;
    // commit iff i-slot real AND a finite candidate exists (high word > ordf(-inf))
    if (g == 0) {
        if (il0 < ni && (unsigned)(k0 >> 32) > 0x007FFFFFu)
            atomicMax(&amax[(size_t)b * HW + ilist[il0]], k0);
        if (il1 < ni && (unsigned)(k1 >> 32) > 0x007FFFFFu)
            atomicMax(&amax[(size_t)b * HW + ilist[il1]], k1);
    }
}

// ---------------- kernel 3: epilogue = shift channels only ----------------
// Channels [0,128) are copied by prep's copy blocks; this kernel only fills
// out channels [128,192): shift = former at argmax j (0 where !flag).
// Keys store compact j -> decode via jlist. amax==0 (nj==0) falls back to
// j=0 = reference argmax of an all-NEG row.
__global__ void epilogue_kernel(const float* __restrict__ x,
                                const int* __restrict__ mask,
                                const unsigned long long* __restrict__ amax,
                                const int* __restrict__ jlist, float4* __restrict__ out4) {
    const int q = HW / 4;                            // 2304
    int t = blockIdx.x * blockDim.x + threadIdx.x;   // 0 .. 2*64*q-1
    if (t >= 2 * 64 * q) return;
    int pos4 = t % q;
    int cs = (t / q) % 64;                           // shift channel 0..63
    int b = t / (64 * q);
    float4 v = make_float4(0.f, 0.f, 0.f, 0.f);
    float* vp = &v.x;
    int pos = pos4 * 4;
    const float* xf = x + (size_t)(b * 128 + cs) * HW;   // former half
#pragma unroll
    for (int k = 0; k < 4; k++) {
        int p = pos + k;
        if (mask[p] >= 1) {
            unsigned long long key = amax[(size_t)b * HW + p];
            int j = 0;
            if (key != 0ull) j = jlist[(int)(~(unsigned int)key)];
            vp[k] = xf[j];
        }
    }
    out4[((size_t)b * 192 + 128 + cs) * q + pos4] = v;
}

extern "C" void kernel_launch(void* const* d_in, const int* in_sizes, int n_in,
                              void* d_out, int out_size, void* d_ws, size_t ws_size,
                              hipStream_t stream) {
    const float* x = (const float*)d_in[0];
    const int* mask = (const int*)d_in[1];
    float4* out4 = (float4*)d_out;

    // workspace layout (frag bases 128B-aligned):
    //   counts @0 (8B) | ilist @128 (36864) | jlist @36992 (36864)
    //   amax @73856 (147456)
    //   aH @221312 | aL | bH | bL  -- each 2*288*4*64*8 f16 = 2359296 B
    // total = 221312 + 4*2359296 = 9658496 B
    char* ws = (char*)d_ws;
    int*   counts = (int*)ws;
    int*   ilist  = (int*)(ws + 128);
    int*   jlist  = (int*)(ws + 36992);
    unsigned long long* amax = (unsigned long long*)(ws + 73856);
    _Float16* aH = (_Float16*)(ws + 221312);
    _Float16* aL = (_Float16*)(ws + 221312 + 1 * 2359296);
    _Float16* bH = (_Float16*)(ws + 221312 + 2 * 2359296);
    _Float16* bL = (_Float16*)(ws + 221312 + 3 * 2359296);

    // 1) prep: scan + norm + split + pack + amax zero, plus 160 copy blocks
    //    doing the amax-independent out[:, :128] passthrough
    prep_kernel<<<288 + NCOPY, 256, 0, stream>>>(x, (const float4*)x, mask,
                                                 ilist, jlist, counts,
                                                 aH, aL, bH, bL, amax, out4);
    // 2) MFMA argmax over compacted space (grid: i-groups, j-chunks, batch)
    {
        dim3 grid(NSTRIP / 8, NCH, 2);               // 36 x 18 x 2 (dead blocks exit)
        argmax_kernel<<<grid, 256, 0, stream>>>(aH, aL, bH, bL, ilist, counts, amax);
    }
    // 3) epilogue: shift channels only (decode + gather)
    {
        int n = 2 * 64 * (HW / 4);
        epilogue_kernel<<<(n + 255) / 256, 256, 0, stream>>>(x, mask, amax, jlist, out4);
    }
}